// Round 5
// baseline (1492.486 us; speedup 1.0000x reference)
//
#include <hip/hip_runtime.h>
#include <hip/hip_fp16.h>

#define C 128
#define C2 64    // half2 per row
#define C4 32    // float4 per fp32 row
#define NCHUNK 4 // channel chunks of 32
#define NBUCK 256

typedef float f4_t __attribute__((ext_vector_type(4)));

// ---------------------------------------------------------------------------
__global__ void zero_cnt_kernel(int* __restrict__ cnt, int n) {
    int i = blockIdx.x * blockDim.x + threadIdx.x;
    if (i < n) cnt[i] = 0;
}

__global__ void count_kernel(const int* __restrict__ dst, int* __restrict__ cnt, int E) {
    int e = blockIdx.x * blockDim.x + threadIdx.x;
    if (e < E) atomicAdd(&cnt[dst[e]], 1);
}

// ---- 3-phase parallel exclusive scan of cnt[0..n) --------------------------
__global__ void scan_reduce_kernel(const int* __restrict__ cnt, int* __restrict__ psum, int n) {
    __shared__ int s[256];
    int t = threadIdx.x;
    int i = blockIdx.x * 256 + t;
    s[t] = (i < n) ? cnt[i] : 0;
    __syncthreads();
    for (int off = 128; off > 0; off >>= 1) {
        if (t < off) s[t] += s[t + off];
        __syncthreads();
    }
    if (t == 0) psum[blockIdx.x] = s[0];
}

__global__ void scan_partials_kernel(const int* __restrict__ psum, int* __restrict__ bpre,
                                     int* __restrict__ offsets, int n, int nb) {
    __shared__ int s[256];
    int t = threadIdx.x;
    s[t] = (t < nb) ? psum[t] : 0;
    __syncthreads();
    for (int off = 1; off < 256; off <<= 1) {
        int v = 0;
        if (t >= off) v = s[t - off];
        __syncthreads();
        if (t >= off) s[t] += v;
        __syncthreads();
    }
    bpre[t] = (t == 0) ? 0 : s[t - 1];
    if (t == 255) offsets[n] = s[255];
}

__global__ void scan_apply_kernel(const int* __restrict__ cnt, const int* __restrict__ bpre,
                                  int* __restrict__ offsets, int* __restrict__ cursor,
                                  float* __restrict__ dinv, int n) {
    __shared__ int s[256];
    int t = threadIdx.x;
    int i = blockIdx.x * 256 + t;
    int c = (i < n) ? cnt[i] : 0;
    s[t] = c;
    __syncthreads();
    for (int off = 1; off < 256; off <<= 1) {
        int v = 0;
        if (t >= off) v = s[t - off];
        __syncthreads();
        if (t >= off) s[t] += v;
        __syncthreads();
    }
    if (i < n) {
        int excl = bpre[blockIdx.x] + s[t] - c;
        offsets[i] = excl;
        cursor[i]  = excl;
        dinv[i]    = rsqrtf((float)(c + 1));
    }
}

// ---- degree bucket sort -> perm (ascending degree) -------------------------
__global__ void hist_zero_kernel(int* __restrict__ hist) { hist[threadIdx.x] = 0; }

__global__ void hist_kernel(const int* __restrict__ cnt, int* __restrict__ hist, int n) {
    int i = blockIdx.x * blockDim.x + threadIdx.x;
    if (i < n) {
        int d = cnt[i]; if (d > NBUCK - 1) d = NBUCK - 1;
        atomicAdd(&hist[d], 1);
    }
}

__global__ void hist_scan_kernel(const int* __restrict__ hist, int* __restrict__ bcur) {
    __shared__ int s[256];
    int t = threadIdx.x;
    s[t] = hist[t];
    __syncthreads();
    for (int off = 1; off < 256; off <<= 1) {
        int v = 0;
        if (t >= off) v = s[t - off];
        __syncthreads();
        if (t >= off) s[t] += v;
        __syncthreads();
    }
    bcur[t] = (t == 0) ? 0 : s[t - 1];
}

__global__ void perm_kernel(const int* __restrict__ cnt, int* __restrict__ bcur,
                            int* __restrict__ perm, int n) {
    int i = blockIdx.x * blockDim.x + threadIdx.x;
    if (i < n) {
        int d = cnt[i]; if (d > NBUCK - 1) d = NBUCK - 1;
        int pos = atomicAdd(&bcur[d], 1);
        perm[pos] = i;
    }
}

// ---- counting-sort scatter: CSR edge array ---------------------------------
__global__ void scatter_kernel(const int* __restrict__ src, const int* __restrict__ dst,
                               int* __restrict__ cursor, int* __restrict__ sorted_src, int E) {
    int e = blockIdx.x * blockDim.x + threadIdx.x;
    if (e < E) {
        int d = dst[e];
        int pos = atomicAdd(&cursor[d], 1);
        sorted_src[pos] = src[e];
    }
}

// hidden = coeffs[0]*x (fp32), y0 = half(dinv[v]*x)
__global__ void init_kernel(const float* __restrict__ x, const float* __restrict__ coeffs,
                            const float* __restrict__ dinv, float2* __restrict__ hidden,
                            __half2* __restrict__ y0, int total2) {
    int i = blockIdx.x * blockDim.x + threadIdx.x;
    if (i >= total2) return;
    int v = i >> 6;  // i / C2
    float dv = dinv[v];
    float2 xv = ((const float2*)x)[i];
    float g0 = coeffs[0];
    hidden[i] = make_float2(g0 * xv.x, g0 * xv.y);
    y0[i] = __floats2half2_rn(dv * xv.x, dv * xv.y);
}

// ---------------------------------------------------------------------------
__device__ __forceinline__ float4 h4_to_f4(uint2 u) {
    __half2 p = *reinterpret_cast<__half2*>(&u.x);
    __half2 q = *reinterpret_cast<__half2*>(&u.y);
    float2 f = __half22float2(p);
    float2 g = __half22float2(q);
    return make_float4(f.x, f.y, g.x, g.y);
}

// one propagation step, channel-chunked.
// block = 256 thr = 4 waves; wave = 8 groups x 8 lanes; group owns 1 node.
// chunk c in [0,4): 32 channels = 64 B of the fp16 row; lane j owns 8 B (half4).
// y working set per chunk = 3.2 MB -> resident in each XCD's 4 MB L2.
__global__ __launch_bounds__(256)
void prop_kernel(const unsigned short* __restrict__ yin, unsigned short* __restrict__ yout,
                 float* __restrict__ hidden, const float* __restrict__ coeffs, int k,
                 const int* __restrict__ offsets, const int* __restrict__ srcs,
                 const float* __restrict__ dinv, const int* __restrict__ perm, int n) {
    int t = threadIdx.x;
    int lane = t & 63;
    int grp  = lane >> 3;          // 0..7 within wave
    int j    = lane & 7;           // 0..7 within group
    int slot = blockIdx.x * 32 + (t >> 6) * 8 + grp;
    if (slot >= n) return;
    int v = perm[slot];
    int beg = offsets[v];
    int end = offsets[v + 1];
    float dv = dinv[v];
    float gamma = coeffs[k];

    for (int c = 0; c < NCHUNK; ++c) {
        int coff = c * 32 + j * 4;         // ushort offset within row
        float4 a0 = {0,0,0,0}, a1 = {0,0,0,0}, a2 = {0,0,0,0}, a3 = {0,0,0,0};
        int e = beg;
        for (; e + 4 <= end; e += 4) {
            int s0 = srcs[e], s1 = srcs[e + 1], s2 = srcs[e + 2], s3 = srcs[e + 3];
            uint2 u0 = *(const uint2*)(yin + (size_t)s0 * C + coff);
            uint2 u1 = *(const uint2*)(yin + (size_t)s1 * C + coff);
            uint2 u2 = *(const uint2*)(yin + (size_t)s2 * C + coff);
            uint2 u3 = *(const uint2*)(yin + (size_t)s3 * C + coff);
            float4 f0 = h4_to_f4(u0), f1 = h4_to_f4(u1), f2 = h4_to_f4(u2), f3 = h4_to_f4(u3);
            a0.x += f0.x; a0.y += f0.y; a0.z += f0.z; a0.w += f0.w;
            a1.x += f1.x; a1.y += f1.y; a1.z += f1.z; a1.w += f1.w;
            a2.x += f2.x; a2.y += f2.y; a2.z += f2.z; a2.w += f2.w;
            a3.x += f3.x; a3.y += f3.y; a3.z += f3.z; a3.w += f3.w;
        }
        for (; e < end; ++e) {
            int s = srcs[e];
            float4 f = h4_to_f4(*(const uint2*)(yin + (size_t)s * C + coff));
            a0.x += f.x; a0.y += f.y; a0.z += f.z; a0.w += f.w;
        }
        float4 self = h4_to_f4(*(const uint2*)(yin + (size_t)v * C + coff));
        float sx = (a0.x + a1.x) + (a2.x + a3.x) + self.x;
        float sy = (a0.y + a1.y) + (a2.y + a3.y) + self.y;
        float sz = (a0.z + a1.z) + (a2.z + a3.z) + self.z;
        float sw = (a0.w + a1.w) + (a2.w + a3.w) + self.w;
        float xnx = dv * sx, xny = dv * sy, xnz = dv * sz, xnw = dv * sw;

        // hidden RMW: pure stream, nontemporal to protect L2 residency of y
        f4_t* hp = (f4_t*)(hidden + (size_t)v * C + c * 32 + j * 4);
        f4_t h = __builtin_nontemporal_load(hp);
        h.x += gamma * xnx; h.y += gamma * xny; h.z += gamma * xnz; h.w += gamma * xnw;
        __builtin_nontemporal_store(h, hp);

        __half2 p = __floats2half2_rn(dv * xnx, dv * xny);
        __half2 q = __floats2half2_rn(dv * xnz, dv * xnw);
        uint2 u;
        u.x = *reinterpret_cast<unsigned int*>(&p);
        u.y = *reinterpret_cast<unsigned int*>(&q);
        *(uint2*)(yout + (size_t)v * C + coff) = u;
    }
}

extern "C" void kernel_launch(void* const* d_in, const int* in_sizes, int n_in,
                              void* d_out, int out_size, void* d_ws, size_t ws_size,
                              hipStream_t stream) {
    const float* x      = (const float*)d_in[0];
    const float* coeffs = (const float*)d_in[1];
    const int*   edge   = (const int*)d_in[2];

    const int N = in_sizes[0] / C;          // 50000
    const int K = in_sizes[1] - 1;          // 10
    const int E = in_sizes[2] / 2;          // 1,600,000
    const int* src = edge;
    const int* dst = edge + E;

    char* ws = (char*)d_ws;
    auto alloc = [&](size_t bytes) -> void* {
        void* p = (void*)ws;
        ws += (bytes + 255) & ~(size_t)255;
        return p;
    };
    int*            cnt        = (int*)alloc((size_t)N * 4);
    int*            offsets    = (int*)alloc((size_t)(N + 1) * 4);
    int*            cursor     = (int*)alloc((size_t)N * 4);
    int*            sorted_src = (int*)alloc((size_t)E * 4);
    float*          dinv       = (float*)alloc((size_t)N * 4);
    int*            psum       = (int*)alloc(256 * 4);
    int*            bpre       = (int*)alloc(256 * 4);
    int*            hist       = (int*)alloc(NBUCK * 4);
    int*            bcur       = (int*)alloc(NBUCK * 4);
    int*            perm       = (int*)alloc((size_t)N * 4);
    unsigned short* buf0       = (unsigned short*)alloc((size_t)N * C * 2);
    unsigned short* buf1       = (unsigned short*)alloc((size_t)N * C * 2);

    const int B = 256;
    const int nb = (N + 255) / 256;   // 196 scan blocks (<= 256)

    zero_cnt_kernel<<<(N + B - 1) / B, B, 0, stream>>>(cnt, N);
    count_kernel<<<(E + B - 1) / B, B, 0, stream>>>(dst, cnt, E);

    scan_reduce_kernel<<<nb, 256, 0, stream>>>(cnt, psum, N);
    scan_partials_kernel<<<1, 256, 0, stream>>>(psum, bpre, offsets, N, nb);
    scan_apply_kernel<<<nb, 256, 0, stream>>>(cnt, bpre, offsets, cursor, dinv, N);

    hist_zero_kernel<<<1, NBUCK, 0, stream>>>(hist);
    hist_kernel<<<(N + B - 1) / B, B, 0, stream>>>(cnt, hist, N);
    hist_scan_kernel<<<1, NBUCK, 0, stream>>>(hist, bcur);
    perm_kernel<<<(N + B - 1) / B, B, 0, stream>>>(cnt, bcur, perm, N);

    scatter_kernel<<<(E + B - 1) / B, B, 0, stream>>>(src, dst, cursor, sorted_src, E);
    init_kernel<<<((size_t)N * C2 + B - 1) / B, B, 0, stream>>>(x, coeffs, dinv,
                                                                (float2*)d_out,
                                                                (__half2*)buf0, N * C2);

    const unsigned short* yin = buf0;
    unsigned short* yout = buf1;
    for (int k = 1; k <= K; ++k) {
        prop_kernel<<<(N + 31) / 32, B, 0, stream>>>(yin, yout, (float*)d_out, coeffs, k,
                                                     offsets, sorted_src, dinv, perm, N);
        yin  = yout;
        yout = (yout == buf0) ? buf1 : buf0;
    }
}

// Round 6
// 1075.018 us; speedup vs baseline: 1.3883x; 1.3883x over previous
//
#include <hip/hip_runtime.h>
#include <hip/hip_fp16.h>

#define C 128
#define C2 64    // half2 per row
#define NBUCK 256

typedef float f4_t __attribute__((ext_vector_type(4)));

// ---------------------------------------------------------------------------
__global__ void zero_cnt_kernel(int* __restrict__ cnt, int n) {
    int i = blockIdx.x * blockDim.x + threadIdx.x;
    if (i < n) cnt[i] = 0;
}

__global__ void count_kernel(const int* __restrict__ dst, int* __restrict__ cnt, int E) {
    int e = blockIdx.x * blockDim.x + threadIdx.x;
    if (e < E) atomicAdd(&cnt[dst[e]], 1);
}

// ---- 3-phase parallel exclusive scan of cnt[0..n) --------------------------
__global__ void scan_reduce_kernel(const int* __restrict__ cnt, int* __restrict__ psum, int n) {
    __shared__ int s[256];
    int t = threadIdx.x;
    int i = blockIdx.x * 256 + t;
    s[t] = (i < n) ? cnt[i] : 0;
    __syncthreads();
    for (int off = 128; off > 0; off >>= 1) {
        if (t < off) s[t] += s[t + off];
        __syncthreads();
    }
    if (t == 0) psum[blockIdx.x] = s[0];
}

__global__ void scan_partials_kernel(const int* __restrict__ psum, int* __restrict__ bpre,
                                     int* __restrict__ offsets, int n, int nb) {
    __shared__ int s[256];
    int t = threadIdx.x;
    s[t] = (t < nb) ? psum[t] : 0;
    __syncthreads();
    for (int off = 1; off < 256; off <<= 1) {
        int v = 0;
        if (t >= off) v = s[t - off];
        __syncthreads();
        if (t >= off) s[t] += v;
        __syncthreads();
    }
    bpre[t] = (t == 0) ? 0 : s[t - 1];
    if (t == 255) offsets[n] = s[255];
}

__global__ void scan_apply_kernel(const int* __restrict__ cnt, const int* __restrict__ bpre,
                                  int* __restrict__ offsets, int* __restrict__ cursor,
                                  float* __restrict__ dinv, int n) {
    __shared__ int s[256];
    int t = threadIdx.x;
    int i = blockIdx.x * 256 + t;
    int c = (i < n) ? cnt[i] : 0;
    s[t] = c;
    __syncthreads();
    for (int off = 1; off < 256; off <<= 1) {
        int v = 0;
        if (t >= off) v = s[t - off];
        __syncthreads();
        if (t >= off) s[t] += v;
        __syncthreads();
    }
    if (i < n) {
        int excl = bpre[blockIdx.x] + s[t] - c;
        offsets[i] = excl;
        cursor[i]  = excl;
        dinv[i]    = rsqrtf((float)(c + 1));
    }
}

// ---- degree bucket sort -> perm (ascending degree) -------------------------
__global__ void hist_zero_kernel(int* __restrict__ hist) { hist[threadIdx.x] = 0; }

__global__ void hist_kernel(const int* __restrict__ cnt, int* __restrict__ hist, int n) {
    int i = blockIdx.x * blockDim.x + threadIdx.x;
    if (i < n) {
        int d = cnt[i]; if (d > NBUCK - 1) d = NBUCK - 1;
        atomicAdd(&hist[d], 1);
    }
}

__global__ void hist_scan_kernel(const int* __restrict__ hist, int* __restrict__ bcur) {
    __shared__ int s[256];
    int t = threadIdx.x;
    s[t] = hist[t];
    __syncthreads();
    for (int off = 1; off < 256; off <<= 1) {
        int v = 0;
        if (t >= off) v = s[t - off];
        __syncthreads();
        if (t >= off) s[t] += v;
        __syncthreads();
    }
    bcur[t] = (t == 0) ? 0 : s[t - 1];
}

__global__ void perm_kernel(const int* __restrict__ cnt, int* __restrict__ bcur,
                            int* __restrict__ perm, int n) {
    int i = blockIdx.x * blockDim.x + threadIdx.x;
    if (i < n) {
        int d = cnt[i]; if (d > NBUCK - 1) d = NBUCK - 1;
        int pos = atomicAdd(&bcur[d], 1);
        perm[pos] = i;
    }
}

// ---- counting-sort scatter: CSR edge array ---------------------------------
__global__ void scatter_kernel(const int* __restrict__ src, const int* __restrict__ dst,
                               int* __restrict__ cursor, int* __restrict__ sorted_src, int E) {
    int e = blockIdx.x * blockDim.x + threadIdx.x;
    if (e < E) {
        int d = dst[e];
        int pos = atomicAdd(&cursor[d], 1);
        sorted_src[pos] = src[e];
    }
}

// hidden = coeffs[0]*x (fp32), y0 = half(dinv[v]*x)
__global__ void init_kernel(const float* __restrict__ x, const float* __restrict__ coeffs,
                            const float* __restrict__ dinv, float2* __restrict__ hidden,
                            __half2* __restrict__ y0, int total2) {
    int i = blockIdx.x * blockDim.x + threadIdx.x;
    if (i >= total2) return;
    int v = i >> 6;  // i / C2
    float dv = dinv[v];
    float2 xv = ((const float2*)x)[i];
    float g0 = coeffs[0];
    hidden[i] = make_float2(g0 * xv.x, g0 * xv.y);
    y0[i] = __floats2half2_rn(dv * xv.x, dv * xv.y);
}

// ---------------------------------------------------------------------------
__device__ __forceinline__ void acc8(float* a, uint4 u) {
    __half2* h = (__half2*)&u;
    #pragma unroll
    for (int i = 0; i < 4; ++i) {
        float2 f = __half22float2(h[i]);
        a[2 * i]     += f.x;
        a[2 * i + 1] += f.y;
    }
}

// one propagation step. block = 256 thr = 4 waves = 16 nodes (16 lanes/node).
// lane j in [0,16) owns 16 B = 8 channels (uint4 = half8). 4-deep edge unroll
// keeps 64 B/lane (1 KB/node) of gathers in flight. Nodes in degree order.
__global__ __launch_bounds__(256)
void prop_kernel(const unsigned short* __restrict__ yin, unsigned short* __restrict__ yout,
                 float* __restrict__ hidden, const float* __restrict__ coeffs, int k,
                 const int* __restrict__ offsets, const int* __restrict__ srcs,
                 const float* __restrict__ dinv, const int* __restrict__ perm, int n) {
    int t = threadIdx.x;
    int lane = t & 63;
    int grp  = lane >> 4;          // node within wave: 0..3
    int j    = lane & 15;          // 16-B slice within row: 0..15
    int slot = blockIdx.x * 16 + (t >> 6) * 4 + grp;
    if (slot >= n) return;
    int v = perm[slot];
    int beg = offsets[v];
    int end = offsets[v + 1];
    float dv = dinv[v];
    float gamma = coeffs[k];

    const uint4* base = (const uint4*)yin;   // row = 16 uint4 (256 B)
    float A0[8] = {0,0,0,0,0,0,0,0};
    float A1[8] = {0,0,0,0,0,0,0,0};
    float A2[8] = {0,0,0,0,0,0,0,0};
    float A3[8] = {0,0,0,0,0,0,0,0};

    int e = beg;
    for (; e + 4 <= end; e += 4) {
        int s0 = srcs[e], s1 = srcs[e + 1], s2 = srcs[e + 2], s3 = srcs[e + 3];
        uint4 u0 = base[(size_t)s0 * 16 + j];
        uint4 u1 = base[(size_t)s1 * 16 + j];
        uint4 u2 = base[(size_t)s2 * 16 + j];
        uint4 u3 = base[(size_t)s3 * 16 + j];
        acc8(A0, u0); acc8(A1, u1); acc8(A2, u2); acc8(A3, u3);
    }
    for (; e < end; ++e) {
        uint4 u = base[(size_t)srcs[e] * 16 + j];
        acc8(A0, u);
    }
    // self-loop term
    uint4 us = base[(size_t)v * 16 + j];
    acc8(A1, us);

    float xn[8];
    #pragma unroll
    for (int i = 0; i < 8; ++i)
        xn[i] = dv * ((A0[i] + A1[i]) + (A2[i] + A3[i]));

    // hidden RMW (pure stream; nontemporal to protect cache residency of y)
    f4_t* hp = (f4_t*)(hidden + (size_t)v * C + j * 8);
    f4_t h0 = __builtin_nontemporal_load(hp);
    f4_t h1 = __builtin_nontemporal_load(hp + 1);
    h0.x += gamma * xn[0]; h0.y += gamma * xn[1]; h0.z += gamma * xn[2]; h0.w += gamma * xn[3];
    h1.x += gamma * xn[4]; h1.y += gamma * xn[5]; h1.z += gamma * xn[6]; h1.w += gamma * xn[7];
    __builtin_nontemporal_store(h0, hp);
    __builtin_nontemporal_store(h1, hp + 1);

    // yout = half(dinv * xn)
    __half2 p0 = __floats2half2_rn(dv * xn[0], dv * xn[1]);
    __half2 p1 = __floats2half2_rn(dv * xn[2], dv * xn[3]);
    __half2 p2 = __floats2half2_rn(dv * xn[4], dv * xn[5]);
    __half2 p3 = __floats2half2_rn(dv * xn[6], dv * xn[7]);
    uint4 u;
    u.x = *reinterpret_cast<unsigned int*>(&p0);
    u.y = *reinterpret_cast<unsigned int*>(&p1);
    u.z = *reinterpret_cast<unsigned int*>(&p2);
    u.w = *reinterpret_cast<unsigned int*>(&p3);
    ((uint4*)yout)[(size_t)v * 16 + j] = u;
}

extern "C" void kernel_launch(void* const* d_in, const int* in_sizes, int n_in,
                              void* d_out, int out_size, void* d_ws, size_t ws_size,
                              hipStream_t stream) {
    const float* x      = (const float*)d_in[0];
    const float* coeffs = (const float*)d_in[1];
    const int*   edge   = (const int*)d_in[2];

    const int N = in_sizes[0] / C;          // 50000
    const int K = in_sizes[1] - 1;          // 10
    const int E = in_sizes[2] / 2;          // 1,600,000
    const int* src = edge;
    const int* dst = edge + E;

    char* ws = (char*)d_ws;
    auto alloc = [&](size_t bytes) -> void* {
        void* p = (void*)ws;
        ws += (bytes + 255) & ~(size_t)255;
        return p;
    };
    int*            cnt        = (int*)alloc((size_t)N * 4);
    int*            offsets    = (int*)alloc((size_t)(N + 1) * 4);
    int*            cursor     = (int*)alloc((size_t)N * 4);
    int*            sorted_src = (int*)alloc((size_t)E * 4);
    float*          dinv       = (float*)alloc((size_t)N * 4);
    int*            psum       = (int*)alloc(256 * 4);
    int*            bpre       = (int*)alloc(256 * 4);
    int*            hist       = (int*)alloc(NBUCK * 4);
    int*            bcur       = (int*)alloc(NBUCK * 4);
    int*            perm       = (int*)alloc((size_t)N * 4);
    unsigned short* buf0       = (unsigned short*)alloc((size_t)N * C * 2);
    unsigned short* buf1       = (unsigned short*)alloc((size_t)N * C * 2);

    const int B = 256;
    const int nb = (N + 255) / 256;   // 196 scan blocks (<= 256)

    zero_cnt_kernel<<<(N + B - 1) / B, B, 0, stream>>>(cnt, N);
    count_kernel<<<(E + B - 1) / B, B, 0, stream>>>(dst, cnt, E);

    scan_reduce_kernel<<<nb, 256, 0, stream>>>(cnt, psum, N);
    scan_partials_kernel<<<1, 256, 0, stream>>>(psum, bpre, offsets, N, nb);
    scan_apply_kernel<<<nb, 256, 0, stream>>>(cnt, bpre, offsets, cursor, dinv, N);

    hist_zero_kernel<<<1, NBUCK, 0, stream>>>(hist);
    hist_kernel<<<(N + B - 1) / B, B, 0, stream>>>(cnt, hist, N);
    hist_scan_kernel<<<1, NBUCK, 0, stream>>>(hist, bcur);
    perm_kernel<<<(N + B - 1) / B, B, 0, stream>>>(cnt, bcur, perm, N);

    scatter_kernel<<<(E + B - 1) / B, B, 0, stream>>>(src, dst, cursor, sorted_src, E);
    init_kernel<<<((size_t)N * C2 + B - 1) / B, B, 0, stream>>>(x, coeffs, dinv,
                                                                (float2*)d_out,
                                                                (__half2*)buf0, N * C2);

    const unsigned short* yin = buf0;
    unsigned short* yout = buf1;
    for (int k = 1; k <= K; ++k) {
        prop_kernel<<<(N + 15) / 16, B, 0, stream>>>(yin, yout, (float*)d_out, coeffs, k,
                                                     offsets, sorted_src, dinv, perm, N);
        yin  = yout;
        yout = (yout == buf0) ? buf1 : buf0;
    }
}

// Round 7
// 1029.587 us; speedup vs baseline: 1.4496x; 1.0441x over previous
//
#include <hip/hip_runtime.h>
#include <hip/hip_fp16.h>

#define C 128
#define C2 64    // half2 per row
#define NBUCK 256
#define NSLICE 8

typedef float f4_t __attribute__((ext_vector_type(4)));

// ---------------------------------------------------------------------------
__global__ void zero_cnt_kernel(int* __restrict__ cnt, int n) {
    int i = blockIdx.x * blockDim.x + threadIdx.x;
    if (i < n) cnt[i] = 0;
}

// sliced count: block b handles dst-slice b&7 only -> XCD-local atomics
__global__ void count_kernel(const int* __restrict__ dst, int* __restrict__ cnt,
                             int E, int nps) {
    int slice = blockIdx.x & 7;
    int chunk = blockIdx.x >> 3;
    int nchunks = gridDim.x >> 3;
    int per = (E + nchunks - 1) / nchunks;
    int beg = chunk * per;
    int end = beg + per; if (end > E) end = E;
    int lo = slice * nps, hi = lo + nps;
    for (int e = beg + threadIdx.x; e < end; e += blockDim.x) {
        int d = dst[e];
        if (d >= lo && d < hi) atomicAdd(&cnt[d], 1);
    }
}

// ---- 3-phase parallel exclusive scan of cnt[0..n) --------------------------
__global__ void scan_reduce_kernel(const int* __restrict__ cnt, int* __restrict__ psum, int n) {
    __shared__ int s[256];
    int t = threadIdx.x;
    int i = blockIdx.x * 256 + t;
    s[t] = (i < n) ? cnt[i] : 0;
    __syncthreads();
    for (int off = 128; off > 0; off >>= 1) {
        if (t < off) s[t] += s[t + off];
        __syncthreads();
    }
    if (t == 0) psum[blockIdx.x] = s[0];
}

__global__ void scan_partials_kernel(const int* __restrict__ psum, int* __restrict__ bpre,
                                     int* __restrict__ offsets, int n, int nb) {
    __shared__ int s[256];
    int t = threadIdx.x;
    s[t] = (t < nb) ? psum[t] : 0;
    __syncthreads();
    for (int off = 1; off < 256; off <<= 1) {
        int v = 0;
        if (t >= off) v = s[t - off];
        __syncthreads();
        if (t >= off) s[t] += v;
        __syncthreads();
    }
    bpre[t] = (t == 0) ? 0 : s[t - 1];
    if (t == 255) offsets[n] = s[255];
}

__global__ void scan_apply_kernel(const int* __restrict__ cnt, const int* __restrict__ bpre,
                                  int* __restrict__ offsets, int* __restrict__ cursor,
                                  float* __restrict__ dinv, int n) {
    __shared__ int s[256];
    int t = threadIdx.x;
    int i = blockIdx.x * 256 + t;
    int c = (i < n) ? cnt[i] : 0;
    s[t] = c;
    __syncthreads();
    for (int off = 1; off < 256; off <<= 1) {
        int v = 0;
        if (t >= off) v = s[t - off];
        __syncthreads();
        if (t >= off) s[t] += v;
        __syncthreads();
    }
    if (i < n) {
        int excl = bpre[blockIdx.x] + s[t] - c;
        offsets[i] = excl;
        cursor[i]  = excl;
        dinv[i]    = rsqrtf((float)(c + 1));
    }
}

// ---- degree bucket sort -> perm (ascending degree) -------------------------
__global__ void hist_zero_kernel(int* __restrict__ hist) { hist[threadIdx.x] = 0; }

__global__ void hist_kernel(const int* __restrict__ cnt, int* __restrict__ hist, int n) {
    int i = blockIdx.x * blockDim.x + threadIdx.x;
    if (i < n) {
        int d = cnt[i]; if (d > NBUCK - 1) d = NBUCK - 1;
        atomicAdd(&hist[d], 1);
    }
}

__global__ void hist_scan_kernel(const int* __restrict__ hist, int* __restrict__ bcur) {
    __shared__ int s[256];
    int t = threadIdx.x;
    s[t] = hist[t];
    __syncthreads();
    for (int off = 1; off < 256; off <<= 1) {
        int v = 0;
        if (t >= off) v = s[t - off];
        __syncthreads();
        if (t >= off) s[t] += v;
        __syncthreads();
    }
    bcur[t] = (t == 0) ? 0 : s[t - 1];
}

__global__ void perm_kernel(const int* __restrict__ cnt, int* __restrict__ bcur,
                            int* __restrict__ perm, int n) {
    int i = blockIdx.x * blockDim.x + threadIdx.x;
    if (i < n) {
        int d = cnt[i]; if (d > NBUCK - 1) d = NBUCK - 1;
        int pos = atomicAdd(&bcur[d], 1);
        perm[pos] = i;
    }
}

// ---- sliced counting-sort scatter: XCD-local CSR writes --------------------
// block b handles dst in slice b&7 -> stores to one contiguous ~0.8 MB CSR
// region from one XCD; lines fill in its L2, write back once.
__global__ void scatter_kernel(const int* __restrict__ src, const int* __restrict__ dst,
                               int* __restrict__ cursor, int* __restrict__ sorted_src,
                               int E, int nps) {
    int slice = blockIdx.x & 7;
    int chunk = blockIdx.x >> 3;
    int nchunks = gridDim.x >> 3;
    int per = (E + nchunks - 1) / nchunks;
    int beg = chunk * per;
    int end = beg + per; if (end > E) end = E;
    int lo = slice * nps, hi = lo + nps;
    for (int e = beg + threadIdx.x; e < end; e += blockDim.x) {
        int d = dst[e];
        if (d >= lo && d < hi) {
            int pos = atomicAdd(&cursor[d], 1);
            sorted_src[pos] = src[e];
        }
    }
}

// hidden = coeffs[0]*x (fp32), y0 = half(dinv[v]*x)
__global__ void init_kernel(const float* __restrict__ x, const float* __restrict__ coeffs,
                            const float* __restrict__ dinv, float2* __restrict__ hidden,
                            __half2* __restrict__ y0, int total2) {
    int i = blockIdx.x * blockDim.x + threadIdx.x;
    if (i >= total2) return;
    int v = i >> 6;  // i / C2
    float dv = dinv[v];
    float2 xv = ((const float2*)x)[i];
    float g0 = coeffs[0];
    hidden[i] = make_float2(g0 * xv.x, g0 * xv.y);
    y0[i] = __floats2half2_rn(dv * xv.x, dv * xv.y);
}

// ---------------------------------------------------------------------------
__device__ __forceinline__ void acc8(float* a, uint4 u) {
    __half2* h = (__half2*)&u;
    #pragma unroll
    for (int i = 0; i < 4; ++i) {
        float2 f = __half22float2(h[i]);
        a[2 * i]     += f.x;
        a[2 * i + 1] += f.y;
    }
}

// one propagation step. block = 256 thr = 4 waves = 16 nodes (16 lanes/node).
// lane j in [0,16) owns 16 B = 8 channels (uint4 = half8). 8-deep edge unroll
// keeps 128 B/lane of gathers in flight. Nodes in degree-sorted order.
__global__ __launch_bounds__(256)
void prop_kernel(const unsigned short* __restrict__ yin, unsigned short* __restrict__ yout,
                 float* __restrict__ hidden, const float* __restrict__ coeffs, int k,
                 const int* __restrict__ offsets, const int* __restrict__ srcs,
                 const float* __restrict__ dinv, const int* __restrict__ perm, int n) {
    int t = threadIdx.x;
    int lane = t & 63;
    int grp  = lane >> 4;          // node within wave: 0..3
    int j    = lane & 15;          // 16-B slice within row: 0..15
    int slot = blockIdx.x * 16 + (t >> 6) * 4 + grp;
    if (slot >= n) return;
    int v = perm[slot];
    int beg = offsets[v];
    int end = offsets[v + 1];
    float dv = dinv[v];
    float gamma = coeffs[k];

    const uint4* base = (const uint4*)yin;   // row = 16 uint4 (256 B)
    float A0[8] = {0,0,0,0,0,0,0,0};
    float A1[8] = {0,0,0,0,0,0,0,0};
    float A2[8] = {0,0,0,0,0,0,0,0};
    float A3[8] = {0,0,0,0,0,0,0,0};

    int e = beg;
    for (; e + 8 <= end; e += 8) {
        int s0 = srcs[e],     s1 = srcs[e + 1], s2 = srcs[e + 2], s3 = srcs[e + 3];
        int s4 = srcs[e + 4], s5 = srcs[e + 5], s6 = srcs[e + 6], s7 = srcs[e + 7];
        uint4 u0 = base[(size_t)s0 * 16 + j];
        uint4 u1 = base[(size_t)s1 * 16 + j];
        uint4 u2 = base[(size_t)s2 * 16 + j];
        uint4 u3 = base[(size_t)s3 * 16 + j];
        uint4 u4 = base[(size_t)s4 * 16 + j];
        uint4 u5 = base[(size_t)s5 * 16 + j];
        uint4 u6 = base[(size_t)s6 * 16 + j];
        uint4 u7 = base[(size_t)s7 * 16 + j];
        acc8(A0, u0); acc8(A1, u1); acc8(A2, u2); acc8(A3, u3);
        acc8(A0, u4); acc8(A1, u5); acc8(A2, u6); acc8(A3, u7);
    }
    for (; e + 4 <= end; e += 4) {
        int s0 = srcs[e], s1 = srcs[e + 1], s2 = srcs[e + 2], s3 = srcs[e + 3];
        uint4 u0 = base[(size_t)s0 * 16 + j];
        uint4 u1 = base[(size_t)s1 * 16 + j];
        uint4 u2 = base[(size_t)s2 * 16 + j];
        uint4 u3 = base[(size_t)s3 * 16 + j];
        acc8(A0, u0); acc8(A1, u1); acc8(A2, u2); acc8(A3, u3);
    }
    for (; e < end; ++e) {
        uint4 u = base[(size_t)srcs[e] * 16 + j];
        acc8(A0, u);
    }
    // self-loop term
    uint4 us = base[(size_t)v * 16 + j];
    acc8(A1, us);

    float xn[8];
    #pragma unroll
    for (int i = 0; i < 8; ++i)
        xn[i] = dv * ((A0[i] + A1[i]) + (A2[i] + A3[i]));

    // hidden RMW (pure stream; nontemporal to protect cache residency of y)
    f4_t* hp = (f4_t*)(hidden + (size_t)v * C + j * 8);
    f4_t h0 = __builtin_nontemporal_load(hp);
    f4_t h1 = __builtin_nontemporal_load(hp + 1);
    h0.x += gamma * xn[0]; h0.y += gamma * xn[1]; h0.z += gamma * xn[2]; h0.w += gamma * xn[3];
    h1.x += gamma * xn[4]; h1.y += gamma * xn[5]; h1.z += gamma * xn[6]; h1.w += gamma * xn[7];
    __builtin_nontemporal_store(h0, hp);
    __builtin_nontemporal_store(h1, hp + 1);

    // yout = half(dinv * xn)
    __half2 p0 = __floats2half2_rn(dv * xn[0], dv * xn[1]);
    __half2 p1 = __floats2half2_rn(dv * xn[2], dv * xn[3]);
    __half2 p2 = __floats2half2_rn(dv * xn[4], dv * xn[5]);
    __half2 p3 = __floats2half2_rn(dv * xn[6], dv * xn[7]);
    uint4 u;
    u.x = *reinterpret_cast<unsigned int*>(&p0);
    u.y = *reinterpret_cast<unsigned int*>(&p1);
    u.z = *reinterpret_cast<unsigned int*>(&p2);
    u.w = *reinterpret_cast<unsigned int*>(&p3);
    ((uint4*)yout)[(size_t)v * 16 + j] = u;
}

extern "C" void kernel_launch(void* const* d_in, const int* in_sizes, int n_in,
                              void* d_out, int out_size, void* d_ws, size_t ws_size,
                              hipStream_t stream) {
    const float* x      = (const float*)d_in[0];
    const float* coeffs = (const float*)d_in[1];
    const int*   edge   = (const int*)d_in[2];

    const int N = in_sizes[0] / C;          // 50000
    const int K = in_sizes[1] - 1;          // 10
    const int E = in_sizes[2] / 2;          // 1,600,000
    const int* src = edge;
    const int* dst = edge + E;

    char* ws = (char*)d_ws;
    auto alloc = [&](size_t bytes) -> void* {
        void* p = (void*)ws;
        ws += (bytes + 255) & ~(size_t)255;
        return p;
    };
    int*            cnt        = (int*)alloc((size_t)N * 4);
    int*            offsets    = (int*)alloc((size_t)(N + 1) * 4);
    int*            cursor     = (int*)alloc((size_t)N * 4);
    int*            sorted_src = (int*)alloc((size_t)E * 4);
    float*          dinv       = (float*)alloc((size_t)N * 4);
    int*            psum       = (int*)alloc(256 * 4);
    int*            bpre       = (int*)alloc(256 * 4);
    int*            hist       = (int*)alloc(NBUCK * 4);
    int*            bcur       = (int*)alloc(NBUCK * 4);
    int*            perm       = (int*)alloc((size_t)N * 4);
    unsigned short* buf0       = (unsigned short*)alloc((size_t)N * C * 2);
    unsigned short* buf1       = (unsigned short*)alloc((size_t)N * C * 2);

    const int B = 256;
    const int nb = (N + 255) / 256;   // 196 scan blocks (<= 256)
    const int nps = (N + NSLICE - 1) / NSLICE;   // 6250 nodes per slice
    const int slice_grid = 8 * 256;              // 8 slices x 256 chunks

    zero_cnt_kernel<<<(N + B - 1) / B, B, 0, stream>>>(cnt, N);
    count_kernel<<<slice_grid, B, 0, stream>>>(dst, cnt, E, nps);

    scan_reduce_kernel<<<nb, 256, 0, stream>>>(cnt, psum, N);
    scan_partials_kernel<<<1, 256, 0, stream>>>(psum, bpre, offsets, N, nb);
    scan_apply_kernel<<<nb, 256, 0, stream>>>(cnt, bpre, offsets, cursor, dinv, N);

    hist_zero_kernel<<<1, NBUCK, 0, stream>>>(hist);
    hist_kernel<<<(N + B - 1) / B, B, 0, stream>>>(cnt, hist, N);
    hist_scan_kernel<<<1, NBUCK, 0, stream>>>(hist, bcur);
    perm_kernel<<<(N + B - 1) / B, B, 0, stream>>>(cnt, bcur, perm, N);

    scatter_kernel<<<slice_grid, B, 0, stream>>>(src, dst, cursor, sorted_src, E, nps);
    init_kernel<<<((size_t)N * C2 + B - 1) / B, B, 0, stream>>>(x, coeffs, dinv,
                                                                (float2*)d_out,
                                                                (__half2*)buf0, N * C2);

    const unsigned short* yin = buf0;
    unsigned short* yout = buf1;
    for (int k = 1; k <= K; ++k) {
        prop_kernel<<<(N + 15) / 16, B, 0, stream>>>(yin, yout, (float*)d_out, coeffs, k,
                                                     offsets, sorted_src, dinv, perm, N);
        yin  = yout;
        yout = (yout == buf0) ? buf1 : buf0;
    }
}

// Round 8
// 851.278 us; speedup vs baseline: 1.7532x; 1.2095x over previous
//
#include <hip/hip_runtime.h>
#include <hip/hip_fp16.h>

#define C 128
#define C2 64    // half2 per row
#define NBUCK 256
#define NSLICE 8

typedef float f4_t __attribute__((ext_vector_type(4)));

// ---------------------------------------------------------------------------
__global__ void zero_cnt_kernel(int* __restrict__ cnt, int n) {
    int i = blockIdx.x * blockDim.x + threadIdx.x;
    if (i < n) cnt[i] = 0;
}

// sliced count: block b handles dst-slice b&7 only -> XCD-local atomics
__global__ void count_kernel(const int* __restrict__ dst, int* __restrict__ cnt,
                             int E, int nps) {
    int slice = blockIdx.x & 7;
    int chunk = blockIdx.x >> 3;
    int nchunks = gridDim.x >> 3;
    int per = (E + nchunks - 1) / nchunks;
    int beg = chunk * per;
    int end = beg + per; if (end > E) end = E;
    int lo = slice * nps, hi = lo + nps;
    for (int e = beg + threadIdx.x; e < end; e += blockDim.x) {
        int d = dst[e];
        if (d >= lo && d < hi) atomicAdd(&cnt[d], 1);
    }
}

// ---- 3-phase parallel exclusive scan of cnt[0..n) --------------------------
__global__ void scan_reduce_kernel(const int* __restrict__ cnt, int* __restrict__ psum, int n) {
    __shared__ int s[256];
    int t = threadIdx.x;
    int i = blockIdx.x * 256 + t;
    s[t] = (i < n) ? cnt[i] : 0;
    __syncthreads();
    for (int off = 128; off > 0; off >>= 1) {
        if (t < off) s[t] += s[t + off];
        __syncthreads();
    }
    if (t == 0) psum[blockIdx.x] = s[0];
}

__global__ void scan_partials_kernel(const int* __restrict__ psum, int* __restrict__ bpre,
                                     int* __restrict__ offsets, int n, int nb) {
    __shared__ int s[256];
    int t = threadIdx.x;
    s[t] = (t < nb) ? psum[t] : 0;
    __syncthreads();
    for (int off = 1; off < 256; off <<= 1) {
        int v = 0;
        if (t >= off) v = s[t - off];
        __syncthreads();
        if (t >= off) s[t] += v;
        __syncthreads();
    }
    bpre[t] = (t == 0) ? 0 : s[t - 1];
    if (t == 255) offsets[n] = s[255];
}

__global__ void scan_apply_kernel(const int* __restrict__ cnt, const int* __restrict__ bpre,
                                  int* __restrict__ offsets, int* __restrict__ cursor,
                                  float* __restrict__ dinv, int n) {
    __shared__ int s[256];
    int t = threadIdx.x;
    int i = blockIdx.x * 256 + t;
    int c = (i < n) ? cnt[i] : 0;
    s[t] = c;
    __syncthreads();
    for (int off = 1; off < 256; off <<= 1) {
        int v = 0;
        if (t >= off) v = s[t - off];
        __syncthreads();
        if (t >= off) s[t] += v;
        __syncthreads();
    }
    if (i < n) {
        int excl = bpre[blockIdx.x] + s[t] - c;
        offsets[i] = excl;
        cursor[i]  = excl;
        dinv[i]    = rsqrtf((float)(c + 1));
    }
}

// ---- degree bucket sort -> perm (ascending degree) -------------------------
__global__ void hist_zero_kernel(int* __restrict__ hist) { hist[threadIdx.x] = 0; }

// LDS-aggregated histogram: 64 blocks grid-stride, one global add per bucket/block
__global__ void hist_kernel(const int* __restrict__ cnt, int* __restrict__ hist, int n) {
    __shared__ int lh[NBUCK];
    int t = threadIdx.x;
    lh[t] = 0;
    __syncthreads();
    for (int i = blockIdx.x * blockDim.x + t; i < n; i += gridDim.x * blockDim.x) {
        int d = cnt[i]; if (d > NBUCK - 1) d = NBUCK - 1;
        atomicAdd(&lh[d], 1);
    }
    __syncthreads();
    int c = lh[t];
    if (c) atomicAdd(&hist[t], c);
}

__global__ void hist_scan_kernel(const int* __restrict__ hist, int* __restrict__ bcur) {
    __shared__ int s[256];
    int t = threadIdx.x;
    s[t] = hist[t];
    __syncthreads();
    for (int off = 1; off < 256; off <<= 1) {
        int v = 0;
        if (t >= off) v = s[t - off];
        __syncthreads();
        if (t >= off) s[t] += v;
        __syncthreads();
    }
    bcur[t] = (t == 0) ? 0 : s[t - 1];
}

// LDS-aggregated bucket scatter: local ranks via LDS atomics, one global
// return-atomic per (block, nonzero bucket) to reserve a contiguous range.
__global__ void perm_kernel(const int* __restrict__ cnt, int* __restrict__ bcur,
                            int* __restrict__ perm, int n) {
    __shared__ int lhist[NBUCK];
    __shared__ int lbase[NBUCK];
    int t = threadIdx.x;
    lhist[t] = 0;
    __syncthreads();
    int i = blockIdx.x * 256 + t;
    int d = 0, lr = 0;
    if (i < n) {
        d = cnt[i]; if (d > NBUCK - 1) d = NBUCK - 1;
        lr = atomicAdd(&lhist[d], 1);
    }
    __syncthreads();
    int c = lhist[t];
    if (c > 0) lbase[t] = atomicAdd(&bcur[t], c);
    __syncthreads();
    if (i < n) perm[lbase[d] + lr] = i;
}

// ---- sliced counting-sort scatter: XCD-local CSR writes --------------------
__global__ void scatter_kernel(const int* __restrict__ src, const int* __restrict__ dst,
                               int* __restrict__ cursor, int* __restrict__ sorted_src,
                               int E, int nps) {
    int slice = blockIdx.x & 7;
    int chunk = blockIdx.x >> 3;
    int nchunks = gridDim.x >> 3;
    int per = (E + nchunks - 1) / nchunks;
    int beg = chunk * per;
    int end = beg + per; if (end > E) end = E;
    int lo = slice * nps, hi = lo + nps;
    for (int e = beg + threadIdx.x; e < end; e += blockDim.x) {
        int d = dst[e];
        if (d >= lo && d < hi) {
            int pos = atomicAdd(&cursor[d], 1);
            sorted_src[pos] = src[e];
        }
    }
}

// hidden = coeffs[0]*x (fp32), y0 = half(dinv[v]*x)
__global__ void init_kernel(const float* __restrict__ x, const float* __restrict__ coeffs,
                            const float* __restrict__ dinv, float2* __restrict__ hidden,
                            __half2* __restrict__ y0, int total2) {
    int i = blockIdx.x * blockDim.x + threadIdx.x;
    if (i >= total2) return;
    int v = i >> 6;  // i / C2
    float dv = dinv[v];
    float2 xv = ((const float2*)x)[i];
    float g0 = coeffs[0];
    hidden[i] = make_float2(g0 * xv.x, g0 * xv.y);
    y0[i] = __floats2half2_rn(dv * xv.x, dv * xv.y);
}

// ---------------------------------------------------------------------------
__device__ __forceinline__ void acc8(float* a, uint4 u) {
    __half2* h = (__half2*)&u;
    #pragma unroll
    for (int i = 0; i < 4; ++i) {
        float2 f = __half22float2(h[i]);
        a[2 * i]     += f.x;
        a[2 * i + 1] += f.y;
    }
}

// one propagation step. block = 256 thr = 4 waves = 16 nodes (16 lanes/node).
__global__ __launch_bounds__(256)
void prop_kernel(const unsigned short* __restrict__ yin, unsigned short* __restrict__ yout,
                 float* __restrict__ hidden, const float* __restrict__ coeffs, int k,
                 const int* __restrict__ offsets, const int* __restrict__ srcs,
                 const float* __restrict__ dinv, const int* __restrict__ perm, int n) {
    int t = threadIdx.x;
    int lane = t & 63;
    int grp  = lane >> 4;          // node within wave: 0..3
    int j    = lane & 15;          // 16-B slice within row: 0..15
    int slot = blockIdx.x * 16 + (t >> 6) * 4 + grp;
    if (slot >= n) return;
    int v = perm[slot];
    int beg = offsets[v];
    int end = offsets[v + 1];
    float dv = dinv[v];
    float gamma = coeffs[k];

    const uint4* base = (const uint4*)yin;   // row = 16 uint4 (256 B)
    float A0[8] = {0,0,0,0,0,0,0,0};
    float A1[8] = {0,0,0,0,0,0,0,0};
    float A2[8] = {0,0,0,0,0,0,0,0};
    float A3[8] = {0,0,0,0,0,0,0,0};

    int e = beg;
    for (; e + 8 <= end; e += 8) {
        int s0 = srcs[e],     s1 = srcs[e + 1], s2 = srcs[e + 2], s3 = srcs[e + 3];
        int s4 = srcs[e + 4], s5 = srcs[e + 5], s6 = srcs[e + 6], s7 = srcs[e + 7];
        uint4 u0 = base[(size_t)s0 * 16 + j];
        uint4 u1 = base[(size_t)s1 * 16 + j];
        uint4 u2 = base[(size_t)s2 * 16 + j];
        uint4 u3 = base[(size_t)s3 * 16 + j];
        uint4 u4 = base[(size_t)s4 * 16 + j];
        uint4 u5 = base[(size_t)s5 * 16 + j];
        uint4 u6 = base[(size_t)s6 * 16 + j];
        uint4 u7 = base[(size_t)s7 * 16 + j];
        acc8(A0, u0); acc8(A1, u1); acc8(A2, u2); acc8(A3, u3);
        acc8(A0, u4); acc8(A1, u5); acc8(A2, u6); acc8(A3, u7);
    }
    for (; e + 4 <= end; e += 4) {
        int s0 = srcs[e], s1 = srcs[e + 1], s2 = srcs[e + 2], s3 = srcs[e + 3];
        uint4 u0 = base[(size_t)s0 * 16 + j];
        uint4 u1 = base[(size_t)s1 * 16 + j];
        uint4 u2 = base[(size_t)s2 * 16 + j];
        uint4 u3 = base[(size_t)s3 * 16 + j];
        acc8(A0, u0); acc8(A1, u1); acc8(A2, u2); acc8(A3, u3);
    }
    for (; e < end; ++e) {
        uint4 u = base[(size_t)srcs[e] * 16 + j];
        acc8(A0, u);
    }
    // self-loop term
    uint4 us = base[(size_t)v * 16 + j];
    acc8(A1, us);

    float xn[8];
    #pragma unroll
    for (int i = 0; i < 8; ++i)
        xn[i] = dv * ((A0[i] + A1[i]) + (A2[i] + A3[i]));

    // hidden RMW (pure stream; nontemporal to protect cache residency of y)
    f4_t* hp = (f4_t*)(hidden + (size_t)v * C + j * 8);
    f4_t h0 = __builtin_nontemporal_load(hp);
    f4_t h1 = __builtin_nontemporal_load(hp + 1);
    h0.x += gamma * xn[0]; h0.y += gamma * xn[1]; h0.z += gamma * xn[2]; h0.w += gamma * xn[3];
    h1.x += gamma * xn[4]; h1.y += gamma * xn[5]; h1.z += gamma * xn[6]; h1.w += gamma * xn[7];
    __builtin_nontemporal_store(h0, hp);
    __builtin_nontemporal_store(h1, hp + 1);

    // yout = half(dinv * xn)
    __half2 p0 = __floats2half2_rn(dv * xn[0], dv * xn[1]);
    __half2 p1 = __floats2half2_rn(dv * xn[2], dv * xn[3]);
    __half2 p2 = __floats2half2_rn(dv * xn[4], dv * xn[5]);
    __half2 p3 = __floats2half2_rn(dv * xn[6], dv * xn[7]);
    uint4 u;
    u.x = *reinterpret_cast<unsigned int*>(&p0);
    u.y = *reinterpret_cast<unsigned int*>(&p1);
    u.z = *reinterpret_cast<unsigned int*>(&p2);
    u.w = *reinterpret_cast<unsigned int*>(&p3);
    ((uint4*)yout)[(size_t)v * 16 + j] = u;
}

extern "C" void kernel_launch(void* const* d_in, const int* in_sizes, int n_in,
                              void* d_out, int out_size, void* d_ws, size_t ws_size,
                              hipStream_t stream) {
    const float* x      = (const float*)d_in[0];
    const float* coeffs = (const float*)d_in[1];
    const int*   edge   = (const int*)d_in[2];

    const int N = in_sizes[0] / C;          // 50000
    const int K = in_sizes[1] - 1;          // 10
    const int E = in_sizes[2] / 2;          // 1,600,000
    const int* src = edge;
    const int* dst = edge + E;

    char* ws = (char*)d_ws;
    auto alloc = [&](size_t bytes) -> void* {
        void* p = (void*)ws;
        ws += (bytes + 255) & ~(size_t)255;
        return p;
    };
    int*            cnt        = (int*)alloc((size_t)N * 4);
    int*            offsets    = (int*)alloc((size_t)(N + 1) * 4);
    int*            cursor     = (int*)alloc((size_t)N * 4);
    int*            sorted_src = (int*)alloc((size_t)E * 4);
    float*          dinv       = (float*)alloc((size_t)N * 4);
    int*            psum       = (int*)alloc(256 * 4);
    int*            bpre       = (int*)alloc(256 * 4);
    int*            hist       = (int*)alloc(NBUCK * 4);
    int*            bcur       = (int*)alloc(NBUCK * 4);
    int*            perm       = (int*)alloc((size_t)N * 4);
    unsigned short* buf0       = (unsigned short*)alloc((size_t)N * C * 2);
    unsigned short* buf1       = (unsigned short*)alloc((size_t)N * C * 2);

    const int B = 256;
    const int nb = (N + 255) / 256;   // 196 scan blocks (<= 256)
    const int nps = (N + NSLICE - 1) / NSLICE;   // 6250 nodes per slice
    const int slice_grid = 8 * 256;              // 8 slices x 256 chunks

    zero_cnt_kernel<<<(N + B - 1) / B, B, 0, stream>>>(cnt, N);
    count_kernel<<<slice_grid, B, 0, stream>>>(dst, cnt, E, nps);

    scan_reduce_kernel<<<nb, 256, 0, stream>>>(cnt, psum, N);
    scan_partials_kernel<<<1, 256, 0, stream>>>(psum, bpre, offsets, N, nb);
    scan_apply_kernel<<<nb, 256, 0, stream>>>(cnt, bpre, offsets, cursor, dinv, N);

    hist_zero_kernel<<<1, NBUCK, 0, stream>>>(hist);
    hist_kernel<<<64, 256, 0, stream>>>(cnt, hist, N);
    hist_scan_kernel<<<1, NBUCK, 0, stream>>>(hist, bcur);
    perm_kernel<<<nb, 256, 0, stream>>>(cnt, bcur, perm, N);

    scatter_kernel<<<slice_grid, B, 0, stream>>>(src, dst, cursor, sorted_src, E, nps);
    init_kernel<<<((size_t)N * C2 + B - 1) / B, B, 0, stream>>>(x, coeffs, dinv,
                                                                (float2*)d_out,
                                                                (__half2*)buf0, N * C2);

    const unsigned short* yin = buf0;
    unsigned short* yout = buf1;
    for (int k = 1; k <= K; ++k) {
        prop_kernel<<<(N + 15) / 16, B, 0, stream>>>(yin, yout, (float*)d_out, coeffs, k,
                                                     offsets, sorted_src, dinv, perm, N);
        yin  = yout;
        yout = (yout == buf0) ? buf1 : buf0;
    }
}